// Round 2
// baseline (280.393 us; speedup 1.0000x reference)
//
#include <hip/hip_runtime.h>

// EdgeLoss: mean(|sobel_x(sr)-sobel_x(hr)| + |sobel_y(sr)-sobel_y(hr)|)
// = mean(|sobel_x(d)| + |sobel_y(d)|), d = sr - hr (conv linearity; abs
// erases the kernel-flip sign). Separable: s=[1,2,1]*d, t=[1,0,-1]*d
// (horiz); gx=[1,2,1]^T*t, gy=[1,0,-1]^T*s (vert).
//
// R6: R5 fixed load serialization but kept the one-shot-block convoy:
// issue 80KB -> vmcnt(0) drain -> compute -> retire -> redispatch. Memory
// pipe idle ~70% of each block's life (31k cyc wall vs ~8k transfer).
// Fix (T3/T4 pattern): persistent strip blocks, 18-row-slot LDS ring,
// counted s_waitcnt vmcnt(16) so the next chunk's DMA stays in flight
// across barriers -- never drain to 0 in the main loop.
//
// Ring math (CH=8): chunk k reads slots (8k..8k+9)%18; chunk k+1's new
// rows land in (8k+10..8k+17)%18 (disjoint); chunk k+2's new rows land in
// (8k..8k+7)%18 -- issued only AFTER compute-k's retire barrier. 18 slots
// x 2 tensors x 4KB = 144 KiB -> 1 block/CU; DMA depth replaces TLP.

#define IMG_H 1024
#define IMG_W 1024
#define IMG_B 32
#define CH 8                      // rows per chunk
#define NCHUNK 8                  // chunks per block -> 64 rows/block
#define STRIPS (IMG_H / (CH * NCHUNK))   // 16 -> grid (16, 32) = 512 blocks
#define RING 18

#define GLOBAL_PTR(p) ((const __attribute__((address_space(1))) void*)(p))
#define LDS_PTR(p)    ((__attribute__((address_space(3))) void*)(p))

__device__ __forceinline__ void row_st_lds(const float* __restrict__ a,
                                           const float* __restrict__ b,
                                           int x0, float m,
                                           float4& s, float4& t) {
    const float4 av = *reinterpret_cast<const float4*>(a + x0);   // ds_read_b128
    const float4 bv = *reinterpret_cast<const float4*>(b + x0);
    float4 d;
    d.x = (av.x - bv.x) * m;
    d.y = (av.y - bv.y) * m;
    d.z = (av.z - bv.z) * m;
    d.w = (av.w - bv.w) * m;
    // horizontal halo straight from LDS; zero at true image edges only
    const float dl = (x0 > 0)         ? (a[x0 - 1] - b[x0 - 1]) * m : 0.f;
    const float dr = (x0 + 4 < IMG_W) ? (a[x0 + 4] - b[x0 + 4]) * m : 0.f;
    s.x = dl  + 2.f * d.x + d.y;
    s.y = d.x + 2.f * d.y + d.z;
    s.z = d.y + 2.f * d.z + d.w;
    s.w = d.z + 2.f * d.w + dr;
    t.x = dl  - d.y;
    t.y = d.x - d.z;
    t.z = d.y - d.w;
    t.w = d.z - dr;
}

__global__ __launch_bounds__(256) void edge_loss_kernel(
        const float* __restrict__ sr, const float* __restrict__ hr,
        float* __restrict__ out, float invN) {
    // 2 * 18 * 1024 * 4 B = 147456 B -> 1 block/CU (160 KiB pool).
    __shared__ __align__(16) float lA[RING][IMG_W];
    __shared__ __align__(16) float lB[RING][IMG_W];

    const int strip = blockIdx.x;
    const int b     = blockIdx.y;
    const int tid   = threadIdx.x;
    const int lane  = tid & 63;
    const int wave  = tid >> 6;
    const int x0    = tid * 4;          // this thread's 4-col strip
    const int wseg  = wave * 256;       // this wave's 256-col row segment
    const size_t img = (size_t)b * IMG_H * IMG_W;
    const int r0 = strip * (CH * NCHUNK);

    // Stage local-row l (global row r0-1+l, clamped) into ring slot.
    // LDS dst is wave-uniform base + lane*16 (HW semantics); global src is
    // per-lane. 2 instructions, no VGPR destination, no intermediate wait.
    auto stage = [&](int l, int slot) {
        const int yc = min(max(r0 - 1 + l, 0), IMG_H - 1);
        const size_t off = img + (size_t)yc * IMG_W + wseg + lane * 4;
        __builtin_amdgcn_global_load_lds(GLOBAL_PTR(sr + off), LDS_PTR(&lA[slot][wseg]), 16, 0, 0);
        __builtin_amdgcn_global_load_lds(GLOBAL_PTR(hr + off), LDS_PTR(&lB[slot][wseg]), 16, 0, 0);
    };

    // ---- prologue: chunk0 window (l=0..9, 20 loads) + chunk1 new rows
    // (l=10..17, 16 loads). Wait for chunk0 only: vmcnt(16).
    #pragma unroll
    for (int l = 0; l < RING; ++l) stage(l, l);
    asm volatile("s_waitcnt vmcnt(16)" ::: "memory");
    __builtin_amdgcn_s_barrier();

    float acc = 0.f;
    int kb = 0;                         // (CH*k) % RING, maintained incrementally

    for (int k = 0; k < NCHUNK; ++k) {
        // ---- compute chunk k from slots (kb .. kb+9) mod RING ----
        const int yTop = r0 + CH * k;                 // first output row
        const float mtop = (yTop > 0) ? 1.f : 0.f;    // window row i=0 is yTop-1
        const float mbot = (yTop + CH < IMG_H) ? 1.f : 0.f;

        float4 s0, t0, s1, t1, s2, t2;
        {
            int sl0 = kb;                      // i = 0 (kb < RING always)
            int sl1 = kb + 1; if (sl1 >= RING) sl1 -= RING;
            row_st_lds(lA[sl0], lB[sl0], x0, mtop, s0, t0);
            row_st_lds(lA[sl1], lB[sl1], x0, 1.f,  s1, t1);
        }
        #pragma unroll
        for (int i = 2; i < CH + 2; ++i) {
            int sl = kb + i; if (sl >= RING) sl -= RING;
            const float m = (i == CH + 1) ? mbot : 1.f;
            row_st_lds(lA[sl], lB[sl], x0, m, s2, t2);

            float gx, gy;
            gx = t0.x + 2.f * t1.x + t2.x;  gy = s0.x - s2.x;  acc += fabsf(gx) + fabsf(gy);
            gx = t0.y + 2.f * t1.y + t2.y;  gy = s0.y - s2.y;  acc += fabsf(gx) + fabsf(gy);
            gx = t0.z + 2.f * t1.z + t2.z;  gy = s0.z - s2.z;  acc += fabsf(gx) + fabsf(gy);
            gx = t0.w + 2.f * t1.w + t2.w;  gy = s0.w - s2.w;  acc += fabsf(gx) + fabsf(gy);

            s0 = s1; t0 = t1; s1 = s2; t1 = t2;
        }

        if (k < NCHUNK - 1) {
            // ---- retire barrier: every wave's ds_reads of slots
            // (kb..kb+7) are complete -> safe to overwrite.
            asm volatile("s_waitcnt lgkmcnt(0)" ::: "memory");
            __builtin_amdgcn_s_barrier();

            if (k < NCHUNK - 2) {
                // issue chunk k+2's new rows: l = CH*k+18 .. CH*k+25,
                // into slots (kb .. kb+7) mod RING (just retired).
                #pragma unroll
                for (int j = 0; j < CH; ++j) {
                    int sl = kb + j; if (sl >= RING) sl -= RING;
                    stage(CH * k + RING + j, sl);
                }
                // chunk k+1's 16 loads landed; k+2's 16 stay in flight.
                asm volatile("s_waitcnt vmcnt(16)" ::: "memory");
            } else {
                // no more prefetch; drain chunk k+1 (last chunk's rows).
                asm volatile("s_waitcnt vmcnt(0)" ::: "memory");
            }
            __builtin_amdgcn_s_barrier();
        }

        kb += CH; if (kb >= RING) kb -= RING;
    }

    // ---- reduction: wave shuffle -> LDS (reuse lA) -> 1 atomic/block ----
    #pragma unroll
    for (int off = 32; off > 0; off >>= 1)
        acc += __shfl_down(acc, off, 64);

    __syncthreads();                 // full drain: all LDS traffic complete
    if (lane == 0) lA[0][wave] = acc;
    __syncthreads();
    if (tid == 0) {
        const float bsum = lA[0][0] + lA[0][1] + lA[0][2] + lA[0][3];
        atomicAdd(out, bsum * invN);
    }
}

extern "C" void kernel_launch(void* const* d_in, const int* in_sizes, int n_in,
                              void* d_out, int out_size, void* d_ws, size_t ws_size,
                              hipStream_t stream) {
    const float* sr = (const float*)d_in[0];
    const float* hr = (const float*)d_in[1];
    float* out = (float*)d_out;

    hipMemsetAsync(out, 0, sizeof(float), stream);

    dim3 grid(STRIPS, IMG_B);
    const float invN = 1.0f / (float)((size_t)IMG_B * IMG_H * IMG_W);
    edge_loss_kernel<<<grid, 256, 0, stream>>>(sr, hr, out, invN);
}